// Round 4
// baseline (729.548 us; speedup 1.0000x reference)
//
#include <hip/hip_runtime.h>

#define BB 256
#define LL 65536
#define TS 1024
#define HIST 256
#define WINW 64
#define DIM 256
#define NPAT 64

typedef short s8v __attribute__((ext_vector_type(8)));
typedef float f4v __attribute__((ext_vector_type(4)));

#define MFMA16(a, b, c) __builtin_amdgcn_mfma_f32_16x16x32_bf16((a), (b), (c), 0, 0, 0)
#define LOG2E 1.44269504f

// ---- fp32 -> bf16 hi/lo split (combined error ~2^-18 relative) ----
__device__ __forceinline__ short bf16rne(float f) {
    unsigned u = __float_as_uint(f);
    unsigned r = (u + 0x7fffu + ((u >> 16) & 1u)) >> 16;
    return (short)r;
}
__device__ __forceinline__ float bf16tof(short h) {
    return __uint_as_float(((unsigned)(unsigned short)h) << 16);
}
__device__ __forceinline__ void split2(float f, short& hi, short& lo) {
    hi = bf16rne(f);
    lo = bf16rne(f - bf16tof(hi));
}

// ---- merged prep: conv_w / keys / shapes -> hi/lo MFMA B-fragments ----
__global__ void prep_all(const float* __restrict__ w, short* __restrict__ wFH,
                         short* __restrict__ wFL,
                         const float* __restrict__ keys, short* __restrict__ kFH,
                         short* __restrict__ kFL,
                         const float* __restrict__ sh, short* __restrict__ sFH,
                         short* __restrict__ sFL) {
    int bid = blockIdx.x;
    s8v hv, lv;
    if (bid < 32) {
        int idx = bid * 256 + threadIdx.x;        // 8192 = 32 qk * 256 d
        int d = idx & 255, qk = idx >> 8;
        int h0 = qk * 8;
#pragma unroll
        for (int j = 0; j < 8; ++j) {
            short h, l; split2(w[d * HIST + h0 + j], h, l);
            hv[j] = h; lv[j] = l;
        }
        *(s8v*)(wFH + (size_t)idx * 8) = hv;
        *(s8v*)(wFL + (size_t)idx * 8) = lv;
    } else if (bid < 40) {
        int idx = (bid - 32) * 256 + threadIdx.x; // 2048 = 32 qk * 64 p
        int p = idx & 63, qk = idx >> 6;
        int d0 = qk * 8;
#pragma unroll
        for (int j = 0; j < 8; ++j) {
            short h, l; split2(keys[(d0 + j) * NPAT + p], h, l);
            hv[j] = h; lv[j] = l;
        }
        *(s8v*)(kFH + (size_t)idx * 8) = hv;
        *(s8v*)(kFL + (size_t)idx * 8) = lv;
    } else {
        int idx = (bid - 40) * 256 + threadIdx.x; // 512 = 8 qk * 64 w
        int ww = idx & 63, qk = idx >> 6;
        int p0 = qk * 8;
#pragma unroll
        for (int j = 0; j < 8; ++j) {
            short h, l; split2(sh[(p0 + j) * WINW + ww], h, l);
            hv[j] = h; lv[j] = l;
        }
        *(s8v*)(sFH + (size_t)idx * 8) = hv;
        *(s8v*)(sFL + (size_t)idx * 8) = lv;
    }
}

#define WELEM 2240           // 31*64 + 256 window elements (per 32-t chunk)

__device__ __forceinline__ int swz(int u) { return u ^ ((u >> 3) & 7); }

template <int CTRL>
__device__ __forceinline__ float dppadd(float x) {
    int t = __builtin_amdgcn_update_dpp(0, __float_as_int(x), CTRL, 0xf, 0xf, true);
    return x + __int_as_float(t);
}

// ---- xs staging for chunk c (tid = 0..255, worker waves) ----
__device__ __forceinline__ void stage_xs(short* xsH, short* xsL,
                                         const float* __restrict__ xb, int c, int tid) {
    const int gbase = c * 32 * WINW - (HIST - 1);
    for (int i = tid; i < WELEM; i += 256) {
        int gi = gbase + i;
        float v = (gi >= 0) ? xb[gi] : 0.0f;
        short h, l; split2(v, h, l);
        int pos = (swz(i >> 3) << 3) | (i & 7);
        xsH[pos] = h; xsL[pos] = l;
    }
}

// ---- scan segment: N sequential softmax steps (bit-identical math to R3 scan) ----
template <int N>
__device__ __forceinline__ void scan_seg(const float* srow,   // &scoresL[ring][0]
                                         int p, short* bH, short* bL,
                                         int k0, float& avg) {
    const float invc = LOG2E / NPAT;
    float sreg[N];
#pragma unroll
    for (int i = 0; i < N; ++i) sreg[i] = srow[(k0 + i) * 64 + p];  // off-chain preload
#pragma unroll
    for (int i = 0; i < N; ++i) {
        float e = exp2f(sreg[i] - avg);
        float w = e;
        w = dppadd<0x111>(w);   // row_shr:1
        w = dppadd<0x112>(w);   // row_shr:2
        w = dppadd<0x114>(w);   // row_shr:4
        w = dppadd<0x118>(w);   // row_shr:8
        w = dppadd<0x142>(w);   // row_bcast:15
        w = dppadd<0x143>(w);   // row_bcast:31
        float t = __int_as_float(__builtin_amdgcn_readlane(__float_as_int(w), 63));
        float pr = e * __builtin_amdgcn_rcpf(t);
        avg = __builtin_fmaf(pr, LOG2E, avg - invc);
        short h, l; split2(pr, h, l);
        const int trow = k0 + i;
        const int col = p ^ ((trow & 7) << 3);
        bH[trow * 64 + col] = h;
        bL[trow * 64 + col] = l;
    }
}

// ---- mega-fused pipeline: one block per batch, 6 waves ----
// waves 0-3: conv GEMM -> hid -> scores GEMM -> scoresL ring (per 32-t chunk)
// wave 4:    sequential softmax scan (chunk c-1), probs -> pb ring (bf16 hi/lo)
// wave 5:    signal MFMA (chunk c-2), out = relu(sig - x)
// LDS rings give each stage a one-chunk lead; barriers are uniform across waves.
__launch_bounds__(384, 1)
__global__ void fused_pipeline(const float* __restrict__ x,
                               const short* __restrict__ wFH, const short* __restrict__ wFL,
                               const short* __restrict__ kFH, const short* __restrict__ kFL,
                               const short* __restrict__ sFH, const short* __restrict__ sFL,
                               const float* __restrict__ conv_b,
                               const float* __restrict__ avg0,
                               float* __restrict__ out) {
    __shared__ __align__(16) short hidH[32 * 256], hidL[32 * 256];   // 16 KB each
    __shared__ __align__(16) float scoresL[2][32 * 64];              // 16 KB ring
    __shared__ __align__(16) short pbH[2][32 * 64], pbL[2][32 * 64]; // 8 KB + 8 KB
    short* xsH = hidH;   // alias rows 0..8 of hid; lifetimes barrier-separated
    short* xsL = hidL;

    const int b = blockIdx.x;
    const int tid = threadIdx.x;
    const int wid = tid >> 6, lane = tid & 63;
    const int m = lane & 15, q = lane >> 4;
    const float* xb = x + (size_t)b * LL;
    float* ob = out + (size_t)b * LL;

    // scan state
    float avg = 0.0f;
    if (wid == 4) avg = avg0[b * NPAT + lane] * LOG2E;

    // prologue: stage chunk 0 window
    if (wid < 4) stage_xs(xsH, xsL, xb, 0, tid);

    for (int c = 0; c < 34; ++c) {
        f4v acc[2][4];   // conv accumulators (workers), live P1 -> P2

        __syncthreads();                               // ---- bar0: P1 ----
        if (wid < 4) {
            if (c < 32) {
                const int nb = wid * 64;
#pragma unroll
                for (int mt = 0; mt < 2; ++mt)
#pragma unroll
                    for (int nt = 0; nt < 4; ++nt) acc[mt][nt] = (f4v)0.0f;
                for (int kt = 0; kt < 8; ++kt) {
                    s8v aH[2], aL[2];
#pragma unroll
                    for (int mt = 0; mt < 2; ++mt) {
                        int row = mt * 16 + m;
                        int su = swz(row * 8 + kt * 4 + q) << 3;
                        aH[mt] = *(const s8v*)&xsH[su];
                        aL[mt] = *(const s8v*)&xsL[su];
                    }
                    s8v bH[4], bL[4];
#pragma unroll
                    for (int nt = 0; nt < 4; ++nt) {
                        size_t bi = ((size_t)(kt * 4 + q) * 256 + nb + nt * 16 + m) * 8;
                        bH[nt] = *(const s8v*)(wFH + bi);
                        bL[nt] = *(const s8v*)(wFL + bi);
                    }
#pragma unroll
                    for (int mt = 0; mt < 2; ++mt)
#pragma unroll
                        for (int nt = 0; nt < 4; ++nt)
                            acc[mt][nt] = MFMA16(aH[mt], bH[nt], acc[mt][nt]);
#pragma unroll
                    for (int mt = 0; mt < 2; ++mt)
#pragma unroll
                        for (int nt = 0; nt < 4; ++nt)
                            acc[mt][nt] = MFMA16(aL[mt], bH[nt], acc[mt][nt]);
#pragma unroll
                    for (int mt = 0; mt < 2; ++mt)
#pragma unroll
                        for (int nt = 0; nt < 4; ++nt)
                            acc[mt][nt] = MFMA16(aH[mt], bL[nt], acc[mt][nt]);
                }
            }
        } else if (wid == 4) {
            if (c >= 1 && c <= 32)
                scan_seg<12>(scoresL[(c - 1) & 1], lane, pbH[(c - 1) & 1],
                             pbL[(c - 1) & 1], 0, avg);
        } else {
            if (c >= 2) {
                const int cs = c - 2;
                const int t0 = cs * 32;
                const short* pH = pbH[cs & 1];
                const short* pL = pbL[cs & 1];
                // shapes fragments (L2-resident, reload per iteration to save VGPRs)
                s8v sbH[2][4], sbL[2][4];
#pragma unroll
                for (int kt = 0; kt < 2; ++kt)
#pragma unroll
                    for (int nt = 0; nt < 4; ++nt) {
                        size_t bi = ((size_t)(kt * 4 + q) * 64 + nt * 16 + m) * 8;
                        sbH[kt][nt] = *(const s8v*)(sFH + bi);
                        sbL[kt][nt] = *(const s8v*)(sFL + bi);
                    }
#pragma unroll
                for (int mt = 0; mt < 2; ++mt) {
                    float xv[4][4];
#pragma unroll
                    for (int nt = 0; nt < 4; ++nt)
#pragma unroll
                        for (int r = 0; r < 4; ++r)
                            xv[nt][r] = xb[(size_t)(t0 + mt * 16 + q * 4 + r) * WINW +
                                           nt * 16 + m];
                    f4v acc2[4];
#pragma unroll
                    for (int nt = 0; nt < 4; ++nt) acc2[nt] = (f4v)0.0f;
#pragma unroll
                    for (int kt = 0; kt < 2; ++kt) {
                        const int rr = mt * 16 + m;
                        const int col = (kt * 32 + q * 8) ^ ((m & 7) << 3);
                        s8v aH = *(const s8v*)&pH[rr * 64 + col];
                        s8v aL = *(const s8v*)&pL[rr * 64 + col];
#pragma unroll
                        for (int nt = 0; nt < 4; ++nt) {
                            acc2[nt] = MFMA16(aH, sbH[kt][nt], acc2[nt]);
                            acc2[nt] = MFMA16(aL, sbH[kt][nt], acc2[nt]);
                            acc2[nt] = MFMA16(aH, sbL[kt][nt], acc2[nt]);
                        }
                    }
#pragma unroll
                    for (int nt = 0; nt < 4; ++nt)
#pragma unroll
                        for (int r = 0; r < 4; ++r) {
                            size_t gi = (size_t)(t0 + mt * 16 + q * 4 + r) * WINW +
                                        nt * 16 + m;
                            ob[gi] = fmaxf(acc2[nt][r] - xv[nt][r], 0.0f);
                        }
                }
            }
        }

        __syncthreads();                               // ---- bar1: P2 ----
        if (wid < 4) {
            if (c < 32) {
                const int nb = wid * 64;
#pragma unroll
                for (int mt = 0; mt < 2; ++mt)
#pragma unroll
                    for (int nt = 0; nt < 4; ++nt) {
                        int d = nb + nt * 16 + m;
                        float bias = conv_b[d];
#pragma unroll
                        for (int r = 0; r < 4; ++r) {
                            int row = mt * 16 + q * 4 + r;
                            float v = fmaxf(acc[mt][nt][r] + bias, 0.0f);
                            short h, l; split2(v, h, l);
                            int dd = d ^ ((row & 7) << 3);   // XOR swizzle
                            hidH[row * 256 + dd] = h;
                            hidL[row * 256 + dd] = l;
                        }
                    }
            }
        } else if (wid == 4) {
            if (c >= 1 && c <= 32)
                scan_seg<10>(scoresL[(c - 1) & 1], lane, pbH[(c - 1) & 1],
                             pbL[(c - 1) & 1], 12, avg);
        }

        __syncthreads();                               // ---- bar2: P3a ----
        if (wid < 4) {
            if (c < 32) {
                const int pb = wid * 16;
                const int sw0 = (m & 7) << 3;
                f4v aHH[2], aLH[2], aHL[2];
#pragma unroll
                for (int mt = 0; mt < 2; ++mt) {
                    aHH[mt] = (f4v)0.0f; aLH[mt] = (f4v)0.0f; aHL[mt] = (f4v)0.0f;
                }
                for (int kt = 0; kt < 8; ++kt) {
                    s8v aH[2], aL[2];
#pragma unroll
                    for (int mt = 0; mt < 2; ++mt) {
                        int off = (mt * 16 + m) * 256 + ((kt * 32 + q * 8) ^ sw0);
                        aH[mt] = *(const s8v*)&hidH[off];
                        aL[mt] = *(const s8v*)&hidL[off];
                    }
                    size_t bi = ((size_t)(kt * 4 + q) * 64 + pb + m) * 8;
                    s8v bH = *(const s8v*)(kFH + bi);
                    s8v bL = *(const s8v*)(kFL + bi);
#pragma unroll
                    for (int mt = 0; mt < 2; ++mt)
                        aHH[mt] = MFMA16(aH[mt], bH, aHH[mt]);
#pragma unroll
                    for (int mt = 0; mt < 2; ++mt)
                        aLH[mt] = MFMA16(aL[mt], bH, aLH[mt]);
#pragma unroll
                    for (int mt = 0; mt < 2; ++mt)
                        aHL[mt] = MFMA16(aH[mt], bL, aHL[mt]);
                }
                float* sdst = scoresL[c & 1];
#pragma unroll
                for (int mt = 0; mt < 2; ++mt) {
                    f4v s = aHH[mt] + aLH[mt] + aHL[mt];
#pragma unroll
                    for (int r = 0; r < 4; ++r) {
                        int t = mt * 16 + q * 4 + r;
                        float v = fminf(fmaxf(s[r], 0.0f), 6.0f) * LOG2E;
                        sdst[t * 64 + pb + m] = v;
                    }
                }
            }
        } else if (wid == 4) {
            if (c >= 1 && c <= 32)
                scan_seg<10>(scoresL[(c - 1) & 1], lane, pbH[(c - 1) & 1],
                             pbL[(c - 1) & 1], 22, avg);
        }

        __syncthreads();                               // ---- bar3: P3b ----
        if (wid < 4 && c < 31)
            stage_xs(xsH, xsL, xb, c + 1, tid);        // safe: hid reads done (bar3)
    }
}

extern "C" void kernel_launch(void* const* d_in, const int* in_sizes, int n_in,
                              void* d_out, int out_size, void* d_ws, size_t ws_size,
                              hipStream_t stream) {
    const float* x      = (const float*)d_in[0];
    const float* avg0   = (const float*)d_in[1];
    const float* conv_w = (const float*)d_in[2];
    const float* conv_b = (const float*)d_in[3];
    const float* keys   = (const float*)d_in[4];
    const float* shapes = (const float*)d_in[5];
    float* out = (float*)d_out;

    char* ws = (char*)d_ws;
    size_t o = 0;
    short* wFH = (short*)(ws + o); o += 8192 * 16;
    short* wFL = (short*)(ws + o); o += 8192 * 16;
    short* kFH = (short*)(ws + o); o += 2048 * 16;
    short* kFL = (short*)(ws + o); o += 2048 * 16;
    short* sFH = (short*)(ws + o); o += 512 * 16;
    short* sFL = (short*)(ws + o); o += 512 * 16;

    prep_all<<<42, 256, 0, stream>>>(conv_w, wFH, wFL, keys, kFH, kFL, shapes, sFH, sFL);
    fused_pipeline<<<dim3(BB), 384, 0, stream>>>(x, wFH, wFL, kFH, kFL, sFH, sFL,
                                                 conv_b, avg0, out);
}

// Round 6
// 429.419 us; speedup vs baseline: 1.6989x; 1.6989x over previous
//
#include <hip/hip_runtime.h>

#define BB 256
#define LL 65536
#define TS 1024
#define HIST 256
#define WINW 64
#define DIM 256
#define NPAT 64

typedef short s8v __attribute__((ext_vector_type(8)));
typedef float f4v __attribute__((ext_vector_type(4)));

#define MFMA16(a, b, c) __builtin_amdgcn_mfma_f32_16x16x32_bf16((a), (b), (c), 0, 0, 0)
#define LOG2E 1.44269504f

// ---- fp32 -> bf16 hi/lo split (combined error ~2^-18 relative) ----
__device__ __forceinline__ short bf16rne(float f) {
    unsigned u = __float_as_uint(f);
    unsigned r = (u + 0x7fffu + ((u >> 16) & 1u)) >> 16;
    return (short)r;
}
__device__ __forceinline__ float bf16tof(short h) {
    return __uint_as_float(((unsigned)(unsigned short)h) << 16);
}
__device__ __forceinline__ void split2(float f, short& hi, short& lo) {
    hi = bf16rne(f);
    lo = bf16rne(f - bf16tof(hi));
}

// ---- merged prep: conv_w / keys / shapes -> hi/lo MFMA B-fragments ----
__global__ void prep_all(const float* __restrict__ w, short* __restrict__ wFH,
                         short* __restrict__ wFL,
                         const float* __restrict__ keys, short* __restrict__ kFH,
                         short* __restrict__ kFL,
                         const float* __restrict__ sh, short* __restrict__ sFH,
                         short* __restrict__ sFL) {
    int bid = blockIdx.x;
    s8v hv, lv;
    if (bid < 32) {
        int idx = bid * 256 + threadIdx.x;        // 8192 = 32 qk * 256 d
        int d = idx & 255, qk = idx >> 8;
        int h0 = qk * 8;
#pragma unroll
        for (int j = 0; j < 8; ++j) {
            short h, l; split2(w[d * HIST + h0 + j], h, l);
            hv[j] = h; lv[j] = l;
        }
        *(s8v*)(wFH + (size_t)idx * 8) = hv;
        *(s8v*)(wFL + (size_t)idx * 8) = lv;
    } else if (bid < 40) {
        int idx = (bid - 32) * 256 + threadIdx.x; // 2048 = 32 qk * 64 p
        int p = idx & 63, qk = idx >> 6;
        int d0 = qk * 8;
#pragma unroll
        for (int j = 0; j < 8; ++j) {
            short h, l; split2(keys[(d0 + j) * NPAT + p], h, l);
            hv[j] = h; lv[j] = l;
        }
        *(s8v*)(kFH + (size_t)idx * 8) = hv;
        *(s8v*)(kFL + (size_t)idx * 8) = lv;
    } else {
        int idx = (bid - 40) * 256 + threadIdx.x; // 512 = 8 qk * 64 w
        int ww = idx & 63, qk = idx >> 6;
        int p0 = qk * 8;
#pragma unroll
        for (int j = 0; j < 8; ++j) {
            short h, l; split2(sh[(p0 + j) * WINW + ww], h, l);
            hv[j] = h; lv[j] = l;
        }
        *(s8v*)(sFH + (size_t)idx * 8) = hv;
        *(s8v*)(sFL + (size_t)idx * 8) = lv;
    }
}

#define WELEM 2240           // 31*64 + 256 window elements

__device__ __forceinline__ int swz(int u) { return u ^ ((u >> 3) & 7); }

// ---- fused conv + relu + (hid @ keys) + relu6; scoresT[b][p][t] pre-scaled by log2e ----
// R2-measured-good: 177 us, (256,4), xs aliases hid, 32KB LDS.
__launch_bounds__(256, 4)
__global__ void scores_mfma(const float* __restrict__ x,
                            const short* __restrict__ wFH, const short* __restrict__ wFL,
                            const short* __restrict__ kFH, const short* __restrict__ kFL,
                            const float* __restrict__ conv_b,
                            float* __restrict__ scoresT) {
    __shared__ __align__(16) short hidH[32 * 256], hidL[32 * 256];   // 16 KB each
    short* xsH = hidH;   // alias: first WELEM*2 bytes, dead after phase 1
    short* xsL = hidL;

    const int b = blockIdx.y, t0 = blockIdx.x * 32;
    const int tid = threadIdx.x;
    const int lane = tid & 63, wid = tid >> 6;
    const int m = lane & 15, q = lane >> 4;

    const float* xb = x + (size_t)b * LL;
    const int gbase = t0 * WINW - (HIST - 1);
    for (int i = tid; i < WELEM; i += 256) {
        int gi = gbase + i;
        float v = (gi >= 0) ? xb[gi] : 0.0f;
        short h, l; split2(v, h, l);
        int pos = (swz(i >> 3) << 3) | (i & 7);
        xsH[pos] = h; xsL[pos] = l;
    }
    __syncthreads();

    // Phase 1: conv GEMM. Wave wid owns d-range [wid*64, +64). Term-major order.
    const int nb = wid * 64;
    f4v acc[2][4];
#pragma unroll
    for (int mt = 0; mt < 2; ++mt)
#pragma unroll
        for (int nt = 0; nt < 4; ++nt) acc[mt][nt] = (f4v)0.0f;

    for (int kt = 0; kt < 8; ++kt) {
        s8v aH[2], aL[2];
#pragma unroll
        for (int mt = 0; mt < 2; ++mt) {
            int row = mt * 16 + m;
            int su = swz(row * 8 + kt * 4 + q) << 3;
            aH[mt] = *(const s8v*)&xsH[su];
            aL[mt] = *(const s8v*)&xsL[su];
        }
        s8v bH[4], bL[4];
#pragma unroll
        for (int nt = 0; nt < 4; ++nt) {
            size_t bi = ((size_t)(kt * 4 + q) * 256 + nb + nt * 16 + m) * 8;
            bH[nt] = *(const s8v*)(wFH + bi);
            bL[nt] = *(const s8v*)(wFL + bi);
        }
#pragma unroll
        for (int mt = 0; mt < 2; ++mt)
#pragma unroll
            for (int nt = 0; nt < 4; ++nt)
                acc[mt][nt] = MFMA16(aH[mt], bH[nt], acc[mt][nt]);
#pragma unroll
        for (int mt = 0; mt < 2; ++mt)
#pragma unroll
            for (int nt = 0; nt < 4; ++nt)
                acc[mt][nt] = MFMA16(aL[mt], bH[nt], acc[mt][nt]);
#pragma unroll
        for (int mt = 0; mt < 2; ++mt)
#pragma unroll
            for (int nt = 0; nt < 4; ++nt)
                acc[mt][nt] = MFMA16(aH[mt], bL[nt], acc[mt][nt]);
    }
    __syncthreads();   // all xs reads done -> hid may overwrite the union

    // Epilogue 1: bias + relu -> hid (bf16 hi/lo, XOR-swizzled rows)
#pragma unroll
    for (int mt = 0; mt < 2; ++mt)
#pragma unroll
        for (int nt = 0; nt < 4; ++nt) {
            int d = nb + nt * 16 + m;
            float bias = conv_b[d];
#pragma unroll
            for (int r = 0; r < 4; ++r) {
                int row = mt * 16 + q * 4 + r;
                float v = fmaxf(acc[mt][nt][r] + bias, 0.0f);
                short h, l; split2(v, h, l);
                int dd = d ^ ((row & 7) << 3);      // XOR swizzle, 8-elem granularity
                hidH[row * 256 + dd] = h;
                hidL[row * 256 + dd] = l;
            }
        }
    __syncthreads();

    // Phase 2: scores GEMM (K=256 over d). Per-term accumulators (6 chains).
    const int pb = wid * 16;
    const int sw0 = (m & 7) << 3;
    f4v aHH[2], aLH[2], aHL[2];
#pragma unroll
    for (int mt = 0; mt < 2; ++mt) {
        aHH[mt] = (f4v)0.0f; aLH[mt] = (f4v)0.0f; aHL[mt] = (f4v)0.0f;
    }
    for (int kt = 0; kt < 8; ++kt) {
        s8v aH[2], aL[2];
#pragma unroll
        for (int mt = 0; mt < 2; ++mt) {
            int off = (mt * 16 + m) * 256 + ((kt * 32 + q * 8) ^ sw0);
            aH[mt] = *(const s8v*)&hidH[off];
            aL[mt] = *(const s8v*)&hidL[off];
        }
        size_t bi = ((size_t)(kt * 4 + q) * 64 + pb + m) * 8;
        s8v bH = *(const s8v*)(kFH + bi);
        s8v bL = *(const s8v*)(kFL + bi);
#pragma unroll
        for (int mt = 0; mt < 2; ++mt)
            aHH[mt] = MFMA16(aH[mt], bH, aHH[mt]);
#pragma unroll
        for (int mt = 0; mt < 2; ++mt)
            aLH[mt] = MFMA16(aL[mt], bH, aLH[mt]);
#pragma unroll
        for (int mt = 0; mt < 2; ++mt)
            aHL[mt] = MFMA16(aH[mt], bL, aHL[mt]);
    }
#pragma unroll
    for (int mt = 0; mt < 2; ++mt) {
        f4v s = aHH[mt] + aLH[mt] + aHL[mt];
        float4 st;
        st.x = fminf(fmaxf(s[0], 0.0f), 6.0f) * LOG2E;
        st.y = fminf(fmaxf(s[1], 0.0f), 6.0f) * LOG2E;
        st.z = fminf(fmaxf(s[2], 0.0f), 6.0f) * LOG2E;
        st.w = fminf(fmaxf(s[3], 0.0f), 6.0f) * LOG2E;
        *(float4*)&scoresT[((size_t)b * NPAT + pb + m) * TS + t0 + mt * 16 + q * 4] = st;
    }
}

template <int CTRL>
__device__ __forceinline__ float dppadd(float x) {
    int t = __builtin_amdgcn_update_dpp(0, __float_as_int(x), CTRL, 0xf, 0xf, true);
    return x + __int_as_float(t);
}

// all-lane 64-wide sum: 4x row_ror dpp (full 16-row sums in every lane), then
// permlane16_swap (+) and permlane32_swap (+). No SALU round-trip.
// CRITICAL: the swap partner must be materialized through an opaque v_mov so the
// register allocator cannot coalesce the two (equal-valued) operands into one
// physical VGPR — R5 failed exactly there (self-swap scrambles the register).
__device__ __forceinline__ float allsum64(float w) {
    w = dppadd<0x121>(w);   // row_ror:1
    w = dppadd<0x122>(w);   // row_ror:2
    w = dppadd<0x124>(w);   // row_ror:4
    w = dppadd<0x128>(w);   // row_ror:8  -> full row sum, all 16 lanes of each row
    float a = w, b;
    asm("v_mov_b32 %0, %1" : "=v"(b) : "v"(a));            // distinct physreg, opaque
    asm("v_permlane16_swap_b32 %0, %1" : "+v"(a), "+v"(b));
    float w2 = a + b;       // + partner 16-group within each 32-half
    float c = w2, d;
    asm("v_mov_b32 %0, %1" : "=v"(d) : "v"(c));
    asm("v_permlane32_swap_b32 %0, %1" : "+v"(c), "+v"(d));
    return c + d;           // + partner 32-half -> full 64-lane total, all lanes
}

// ---- fused scan + signal: producer-consumer, one block per batch ----
#define CHUNK 64
#define NCHUNK (TS / CHUNK)

__launch_bounds__(128, 1)
__global__ void scan_signal(const float* __restrict__ scoresT,
                            const float* __restrict__ avg0,
                            const short* __restrict__ sFH, const short* __restrict__ sFL,
                            const float* __restrict__ x,
                            float* __restrict__ out) {
    __shared__ __align__(16) short pbH[2][CHUNK][64], pbL[2][CHUNK][64];  // 16KB + 16KB

    const int b = blockIdx.x;
    const int tid = threadIdx.x;
    const int wid = tid >> 6, lane = tid & 63;

    if (wid == 0) {
        // ================= scan wave =================
        // Chain per step: allsum(e) -> rcp -> fma(x') -> exp -> next allsum.
        // pr, avg-update, bf16 split/store all run off-chain.
        const int p = lane;
        const float4* sc = (const float4*)(scoresT + ((size_t)b * NPAT + p) * TS);
        float avg = avg0[b * NPAT + p] * LOG2E;
        const float invc = LOG2E / NPAT;

        float4 buf[4];
#pragma unroll
        for (int s = 0; s < 4; ++s) buf[s] = sc[s];

        float e = __builtin_amdgcn_exp2f(((float*)&buf[0])[0] - avg);

        for (int c = 0; c < NCHUNK; ++c) {
            short* bH = &pbH[c & 1][0][0];
            short* bL = &pbL[c & 1][0][0];
            for (int kb = 0; kb < 16; kb += 4) {
#pragma unroll
                for (int s = 0; s < 4; ++s) {
                    const int g = c * 16 + kb + s;
                    float4 v = buf[s];
                    float* a = (float*)&v;
                    // next group's first elem: slot (s+1)&3 (for s=3: refilled at s=0)
                    const float nx0 = ((float*)&buf[(s + 1) & 3])[0];
#pragma unroll
                    for (int j = 0; j < 4; ++j) {
                        const float snext = (j < 3) ? a[j + 1] : nx0;
                        const float C = (snext + invc) - avg;    // off-chain
                        const float B = e * LOG2E;               // off-chain
                        const float t = allsum64(e);             // chain
                        const float r = __builtin_amdgcn_rcpf(t);// chain
                        const float pr = e * r;                  // off-chain
                        const float xn = __builtin_fmaf(-B, r, C);        // chain
                        const float en = __builtin_amdgcn_exp2f(xn);      // chain
                        avg = __builtin_fmaf(pr, LOG2E, avg - invc);      // off-chain
                        short h, l; split2(pr, h, l);
                        const int trow = (kb + s) * 4 + j;
                        const int col = p ^ ((trow & 7) << 3);
                        bH[trow * 64 + col] = h;
                        bL[trow * 64 + col] = l;
                        e = en;
                    }
                    if (g + 4 < TS / 4) buf[s] = sc[g + 4];  // deep-in-flight refill
                }
            }
            __syncthreads();   // chunk c ready for wave 1
        }
        __syncthreads();       // cover wave 1's consumption of the last chunk
    } else {
        // ================= signal wave =================
        const int m = lane & 15, q = lane >> 4;
        s8v sbH[2][4], sbL[2][4];
#pragma unroll
        for (int kt = 0; kt < 2; ++kt)
#pragma unroll
            for (int nt = 0; nt < 4; ++nt) {
                size_t bi = ((size_t)(kt * 4 + q) * 64 + nt * 16 + m) * 8;
                sbH[kt][nt] = *(const s8v*)(sFH + bi);
                sbL[kt][nt] = *(const s8v*)(sFL + bi);
            }
        const float* xb = x + (size_t)b * LL;
        float* ob = out + (size_t)b * LL;

        __syncthreads();       // wave 0 filling chunk 0
        for (int cc = 0; cc < NCHUNK; ++cc) {
            const short* pH = &pbH[cc & 1][0][0];
            const short* pL = &pbL[cc & 1][0][0];
            const int t0 = cc * CHUNK;
#pragma unroll
            for (int mt = 0; mt < 4; ++mt) {
                float xv[4][4];
#pragma unroll
                for (int nt = 0; nt < 4; ++nt)
#pragma unroll
                    for (int r = 0; r < 4; ++r)
                        xv[nt][r] = xb[(size_t)(t0 + mt * 16 + q * 4 + r) * WINW +
                                       nt * 16 + m];
                f4v acc[4];
#pragma unroll
                for (int nt = 0; nt < 4; ++nt) acc[nt] = (f4v)0.0f;
#pragma unroll
                for (int kt = 0; kt < 2; ++kt) {
                    const int rr = mt * 16 + m;
                    const int col = (kt * 32 + q * 8) ^ ((m & 7) << 3);
                    s8v aH = *(const s8v*)&pH[rr * 64 + col];
                    s8v aL = *(const s8v*)&pL[rr * 64 + col];
#pragma unroll
                    for (int nt = 0; nt < 4; ++nt) {
                        acc[nt] = MFMA16(aH, sbH[kt][nt], acc[nt]);
                        acc[nt] = MFMA16(aL, sbH[kt][nt], acc[nt]);
                        acc[nt] = MFMA16(aH, sbL[kt][nt], acc[nt]);
                    }
                }
#pragma unroll
                for (int nt = 0; nt < 4; ++nt)
#pragma unroll
                    for (int r = 0; r < 4; ++r) {
                        size_t gi = (size_t)(t0 + mt * 16 + q * 4 + r) * WINW +
                                    nt * 16 + m;
                        ob[gi] = fmaxf(acc[nt][r] - xv[nt][r], 0.0f);
                    }
            }
            __syncthreads();   // done with this buffer; wave 0 may reuse it
        }
    }
}

extern "C" void kernel_launch(void* const* d_in, const int* in_sizes, int n_in,
                              void* d_out, int out_size, void* d_ws, size_t ws_size,
                              hipStream_t stream) {
    const float* x      = (const float*)d_in[0];
    const float* avg0   = (const float*)d_in[1];
    const float* conv_w = (const float*)d_in[2];
    const float* conv_b = (const float*)d_in[3];
    const float* keys   = (const float*)d_in[4];
    const float* shapes = (const float*)d_in[5];
    float* out = (float*)d_out;

    char* ws = (char*)d_ws;
    size_t o = 0;
    float* scoresT = (float*)(ws + o); o += (size_t)BB * TS * NPAT * 4;   // 64 MB
    short* wFH = (short*)(ws + o); o += 8192 * 16;
    short* wFL = (short*)(ws + o); o += 8192 * 16;
    short* kFH = (short*)(ws + o); o += 2048 * 16;
    short* kFL = (short*)(ws + o); o += 2048 * 16;
    short* sFH = (short*)(ws + o); o += 512 * 16;
    short* sFL = (short*)(ws + o); o += 512 * 16;

    prep_all<<<42, 256, 0, stream>>>(conv_w, wFH, wFL, keys, kFH, kFL, shapes, sFH, sFL);
    scores_mfma<<<dim3(TS / 32, BB), 256, 0, stream>>>(x, wFH, wFL, kFH, kFL, conv_b, scoresT);
    scan_signal<<<dim3(BB), 128, 0, stream>>>(scoresT, avg0, sFH, sFL, x, out);
}